// Round 2
// baseline (1562.235 us; speedup 1.0000x reference)
//
#include <hip/hip_runtime.h>
#include <stdint.h>

typedef unsigned short u16;
typedef __bf16 bf16x8 __attribute__((ext_vector_type(8)));
typedef float f32x4 __attribute__((ext_vector_type(4)));

__device__ __forceinline__ u16 f2bf(float f) {
    union { float f; unsigned u; } v; v.f = f;
    unsigned r = v.u + 0x7fffu + ((v.u >> 16) & 1u);
    return (u16)(r >> 16);
}
__device__ __forceinline__ float bf2f(u16 h) {
    union { unsigned u; float f; } v; v.u = ((unsigned)h) << 16; return v.f;
}
__device__ __forceinline__ bf16x8 as_frag(uint4 u) {
    union { uint4 u; bf16x8 b; } v; v.u = u; return v.b;
}
__device__ __forceinline__ bf16x8 ldg_frag(const u16* p) {
    return as_frag(*reinterpret_cast<const uint4*>(p));
}
// weight-row permutation so swapped-GEMM output is lane-local in frag order
__device__ __forceinline__ int rowmap(int t, int i) {
    return 32 * (t >> 1) + 8 * (i >> 2) + 4 * (t & 1) + (i & 3);
}

// ---- standard orientation: C[row=edge/node][col=chan] (for node kernels) ----
template <int KT>
__device__ __forceinline__ void gemm_acc(const bf16x8* a, const u16* __restrict__ W, int ldw,
                                         f32x4* acc, int c16, int q4) {
#pragma unroll
    for (int n = 0; n < 8; n++) {
        const u16* wp = W + (size_t)(n * 16 + c16) * ldw + q4 * 8;
#pragma unroll
        for (int k = 0; k < KT; k++) {
            bf16x8 b = ldg_frag(wp + k * 32);
            acc[n] = __builtin_amdgcn_mfma_f32_16x16x32_bf16(a[k], b, acc[n], 0, 0, 0);
        }
    }
}

// ---- swapped orientation: A=weight frags (pre-permuted rows), B=activation frags ----
// output: lane (c16,q4) reg (t,r) = Y[edge=c16][chan per rowmap] (= natural kcol order when packed)
template <int KT>
__device__ __forceinline__ void gemm_T(const bf16x8* bfr, const u16* __restrict__ Wp, int ldw,
                                       f32x4* acc, int c16, int q4) {
#pragma unroll
    for (int t = 0; t < 8; t++) {
        const u16* wp = Wp + (size_t)(t * 16 + c16) * ldw + q4 * 8;
#pragma unroll
        for (int k = 0; k < KT; k++) {
            bf16x8 a = ldg_frag(wp + k * 32);
            acc[t] = __builtin_amdgcn_mfma_f32_16x16x32_bf16(a, bfr[k], acc[t], 0, 0, 0);
        }
    }
}

// GroupNorm on swapped layout: lane holds 32 chans of one edge; reduce across 4 q4-groups
__device__ __forceinline__ void gn_t(f32x4* acc, const float* __restrict__ gb, bool relu, int q4) {
    float s = 0.f, s2 = 0.f;
#pragma unroll
    for (int t = 0; t < 8; t++)
#pragma unroll
        for (int r = 0; r < 4; r++) { float x = acc[t][r]; s += x; s2 = fmaf(x, x, s2); }
    s += __shfl_xor(s, 16, 64); s += __shfl_xor(s, 32, 64);
    s2 += __shfl_xor(s2, 16, 64); s2 += __shfl_xor(s2, 32, 64);
    float mean = s * (1.f / 128.f);
    float var = fmaf(s2, 1.f / 128.f, -mean * mean);
    float rstd = rsqrtf(var + 1e-5f);
#pragma unroll
    for (int t = 0; t < 8; t++) {
        const float4* g4 = reinterpret_cast<const float4*>(gb + (t * 16 + q4 * 4) * 2);
        float4 p01 = g4[0], p23 = g4[1];  // {g0,b0,g1,b1},{g2,b2,g3,b3}
        float gv[4] = {p01.x, p01.z, p23.x, p23.z};
        float bv[4] = {p01.y, p01.w, p23.y, p23.w};
#pragma unroll
        for (int r = 0; r < 4; r++) {
            float y = fmaf((acc[t][r] - mean) * rstd, gv[r], bv[r]);
            acc[t][r] = relu ? fmaxf(y, 0.f) : y;
        }
    }
}

__device__ __forceinline__ bf16x8 pack_frag(f32x4 lo, f32x4 hi) {
    union { u16 s[8]; bf16x8 b; } t;
#pragma unroll
    for (int j = 0; j < 4; j++) { t.s[j] = f2bf(lo[j]); t.s[4 + j] = f2bf(hi[j]); }
    return t.b;
}

// GroupNorm on C-layout acc[n][r] (node kernels)
__device__ __forceinline__ void gn_c(f32x4* acc, const float* __restrict__ g,
                                     const float* __restrict__ b, bool relu, int c16) {
    float gs[8], bs[8];
#pragma unroll
    for (int n = 0; n < 8; n++) { gs[n] = g[n * 16 + c16]; bs[n] = b[n * 16 + c16]; }
#pragma unroll
    for (int r = 0; r < 4; r++) {
        float s = 0.f, s2 = 0.f;
#pragma unroll
        for (int n = 0; n < 8; n++) { float x = acc[n][r]; s += x; s2 = fmaf(x, x, s2); }
#pragma unroll
        for (int m = 1; m < 16; m <<= 1) { s += __shfl_xor(s, m, 64); s2 += __shfl_xor(s2, m, 64); }
        float mean = s * (1.f / 128.f);
        float var = fmaf(s2, 1.f / 128.f, -mean * mean);
        float rstd = rsqrtf(var + 1e-5f);
#pragma unroll
        for (int n = 0; n < 8; n++) {
            float y = fmaf((acc[n][r] - mean) * rstd, gs[n], bs[n]);
            acc[n][r] = relu ? fmaxf(y, 0.f) : y;
        }
    }
}

// ---------------- prep: bf16 conversion, weight-row permutation, gb tables ----------------
__global__ __launch_bounds__(256) void k_prep(
    const float* __restrict__ dW2s, const float* __restrict__ qWs, const float* __restrict__ cW1s,
    const float* __restrict__ cW2s, const float* __restrict__ aWs, const float* __restrict__ lWs,
    const float* __restrict__ actors, const float* __restrict__ metaW,
    const float* __restrict__ dW1s, const float* __restrict__ db1s,
    const float* __restrict__ dg2s, const float* __restrict__ dbt2s,
    const float* __restrict__ qgs, const float* __restrict__ qbs,
    const float* __restrict__ cg1s, const float* __restrict__ cb1s,
    u16* __restrict__ o_dW2p, u16* __restrict__ o_qWp, u16* __restrict__ o_cW1p,
    u16* __restrict__ o_cW2, u16* __restrict__ o_aW, u16* __restrict__ o_lW,
    u16* __restrict__ o_actb, u16* __restrict__ o_mWf, float* __restrict__ o_mWe,
    float* __restrict__ o_dw1p, float* __restrict__ o_gb) {
    int idx = blockIdx.x * 256 + threadIdx.x;
    if (idx >= 412672) return;
    if (idx < 32768) {
        int i = idx >> 14, rem = idx & 16383, ro = rem >> 7, col = rem & 127;
        o_dW2p[idx] = f2bf(dW2s[i * 16384 + rowmap(ro >> 4, ro & 15) * 128 + col]);
    } else if (idx < 65536) {
        int j = idx - 32768, i = j >> 14, rem = j & 16383, ro = rem >> 7, col = rem & 127;
        o_qWp[j] = f2bf(qWs[i * 16384 + rowmap(ro >> 4, ro & 15) * 128 + col]);
    } else if (idx < 163840) {
        int j = idx - 65536, i = j / 49152, rem = j - i * 49152, ro = rem / 384, col = rem - ro * 384;
        o_cW1p[j] = f2bf(cW1s[i * 49152 + rowmap(ro >> 4, ro & 15) * 384 + col]);
    } else if (idx < 196608) { int j = idx - 163840; o_cW2[j] = f2bf(cW2s[j]); }
    else if (idx < 229376) { int j = idx - 196608; o_aW[j] = f2bf(aWs[j]); }
    else if (idx < 262144) { int j = idx - 229376; o_lW[j] = f2bf(lWs[j]); }
    else if (idx < 393216) { int j = idx - 262144; o_actb[j] = f2bf(actors[j]); }
    else if (idx < 409600) { int j = idx - 393216; o_mWf[j] = f2bf(metaW[(j >> 7) * 132 + (j & 127)]); }
    else if (idx < 410112) { int j = idx - 409600; o_mWe[j] = metaW[(j >> 2) * 132 + 128 + (j & 3)]; }
    else if (idx < 411136) {
        int j = idx - 410112, i = j >> 9, col = (j >> 2) & 127, t = j & 3;
        float v = (t == 0) ? dW1s[i * 256 + col * 2]
                : (t == 1) ? dW1s[i * 256 + col * 2 + 1]
                : (t == 2) ? db1s[i * 128 + col] : 0.f;
        o_dw1p[j] = v;
    } else {
        int j = idx - 411136;           // 3 tables x 2 layers x 128 x {g,b}
        int tb = j >> 9, rem = j & 511, i = rem >> 8, q = rem & 255, o = q >> 1, f = q & 1;
        const float* gsrc = (tb == 0) ? dg2s : (tb == 1) ? qgs : cg1s;
        const float* bsrc = (tb == 0) ? dbt2s : (tb == 1) ? qbs : cb1s;
        int src = i * 128 + rowmap(o >> 4, o & 15);
        o_gb[j] = f ? bsrc[src] : gsrc[src];
    }
}

// ---------------- meta: feat = relu(GN(concat(feat,turn,ctrl,inter) @ mW^T)) ----------------
__global__ __launch_bounds__(256) void k_meta(
    const float* __restrict__ feat, const float* __restrict__ turn,
    const float* __restrict__ ctrl, const float* __restrict__ inter,
    const u16* __restrict__ mWf, const float* __restrict__ mWe,
    const float* __restrict__ g, const float* __restrict__ b, u16* __restrict__ out) {
    int lane = threadIdx.x & 63, wv = threadIdx.x >> 6;
    int c16 = lane & 15, q4 = lane >> 4;
    int m0 = (blockIdx.x * 4 + wv) * 16;
    bf16x8 a[4];
    const float* xr = feat + (size_t)(m0 + c16) * 128 + q4 * 8;
#pragma unroll
    for (int k = 0; k < 4; k++) {
        float4 u0 = *reinterpret_cast<const float4*>(xr + k * 32);
        float4 u1 = *reinterpret_cast<const float4*>(xr + k * 32 + 4);
        union { u16 s[8]; bf16x8 b; } t;
        t.s[0] = f2bf(u0.x); t.s[1] = f2bf(u0.y); t.s[2] = f2bf(u0.z); t.s[3] = f2bf(u0.w);
        t.s[4] = f2bf(u1.x); t.s[5] = f2bf(u1.y); t.s[6] = f2bf(u1.z); t.s[7] = f2bf(u1.w);
        a[k] = t.b;
    }
    f32x4 acc[8] = {};
    gemm_acc<4>(a, mWf, 128, acc, c16, q4);
#pragma unroll
    for (int r = 0; r < 4; r++) {
        int row = m0 + q4 * 4 + r;
        float t0 = turn[2 * row], t1 = turn[2 * row + 1];
        float cv = ctrl[row], iv = inter[row];
#pragma unroll
        for (int n = 0; n < 8; n++) {
            int col = n * 16 + c16;
            float4 we = reinterpret_cast<const float4*>(mWe)[col];
            acc[n][r] += t0 * we.x + t1 * we.y + cv * we.z + iv * we.w;
        }
    }
    gn_c(acc, g, b, true, c16);
#pragma unroll
    for (int r = 0; r < 4; r++) {
        size_t row = m0 + q4 * 4 + r;
#pragma unroll
        for (int n = 0; n < 8; n++) out[row * 128 + n * 16 + c16] = f2bf(acc[n][r]);
    }
}

// ---------------- nodeA: a = feat@aW^T (f32 scatter target init) ----------------
__global__ __launch_bounds__(256) void k_nodeA(
    const u16* __restrict__ featb, const u16* __restrict__ aW, float* __restrict__ a_out) {
    int lane = threadIdx.x & 63, wv = threadIdx.x >> 6;
    int c16 = lane & 15, q4 = lane >> 4;
    int m0 = (blockIdx.x * 4 + wv) * 16;
    bf16x8 a[4];
    const u16* xr = featb + (size_t)(m0 + c16) * 128 + q4 * 8;
#pragma unroll
    for (int k = 0; k < 4; k++) a[k] = ldg_frag(xr + k * 32);
    f32x4 acca[8] = {};
    gemm_acc<4>(a, aW, 128, acca, c16, q4);
#pragma unroll
    for (int r = 0; r < 4; r++) {
        size_t row = m0 + q4 * 4 + r;
#pragma unroll
        for (int n = 0; n < 8; n++) a_out[row * 128 + n * 16 + c16] = acca[n][r];
    }
}

// ---------------- edge: fully register-resident chain, zero LDS, zero barriers ----------------
__global__ __launch_bounds__(256) void k_edge(
    const int* __restrict__ hi, const int* __restrict__ wi,
    const float* __restrict__ mctr, const float* __restrict__ actr,
    const float* __restrict__ dw1p, const u16* __restrict__ dW2p,
    const float* __restrict__ gb_d2,
    const u16* __restrict__ featb, const u16* __restrict__ qWp,
    const float* __restrict__ gb_q,
    const u16* __restrict__ actb, const u16* __restrict__ cW1p,
    const float* __restrict__ gb_c1,
    const u16* __restrict__ cW2, float* __restrict__ a_out) {
    int lane = threadIdx.x & 63, wv = threadIdx.x >> 6;
    int c16 = lane & 15, q4 = lane >> 4;
    int bid = (int)blockIdx.x;
    bid = (bid & 7) * 512 + (bid >> 3);  // XCD-chunked swizzle (4096 = 8*512, bijective)
    int e = bid * 64 + wv * 16 + c16;
    int h = hi[e], w = wi[e];
    float d0x = mctr[2 * h] - actr[2 * w];
    float d0y = mctr[2 * h + 1] - actr[2 * w + 1];
    // d1 = relu(d0 @ dW1^T + db1), built directly in B-frag layout
    bf16x8 bd1[4];
    const float4* w4p = reinterpret_cast<const float4*>(dw1p);
#pragma unroll
    for (int k = 0; k < 4; k++) {
        union { u16 s[8]; bf16x8 b; } t;
#pragma unroll
        for (int j = 0; j < 8; j++) {
            float4 w4 = w4p[k * 32 + q4 * 8 + j];
            t.s[j] = f2bf(fmaxf(fmaf(d0x, w4.x, fmaf(d0y, w4.y, w4.z)), 0.f));
        }
        bd1[k] = t.b;
    }
    // d2 = relu(GN(d1 @ dW2^T)) — swapped GEMM, lane-local output
    f32x4 acc1[8] = {};
    gemm_T<4>(bd1, dW2p, 128, acc1, c16, q4);
    gn_t(acc1, gb_d2, true, q4);
    // q = relu(GN(feat[h] @ qW^T)) — per-edge (row-wise GN == node-wise)
    bf16x8 bq[4];
    const u16* fr = featb + (size_t)h * 128 + q4 * 8;
#pragma unroll
    for (int k = 0; k < 4; k++) bq[k] = ldg_frag(fr + k * 32);
    f32x4 accq[8] = {};
    gemm_T<4>(bq, qWp, 128, accq, c16, q4);
    gn_t(accq, gb_q, true, q4);
    // concat B-frags: [d2 | q | actors[w]]
    bf16x8 bc[12];
#pragma unroll
    for (int k = 0; k < 4; k++) bc[k] = pack_frag(acc1[2 * k], acc1[2 * k + 1]);
#pragma unroll
    for (int k = 0; k < 4; k++) bc[4 + k] = pack_frag(accq[2 * k], accq[2 * k + 1]);
    const u16* ar = actb + (size_t)w * 128 + q4 * 8;
#pragma unroll
    for (int k = 0; k < 4; k++) bc[8 + k] = ldg_frag(ar + k * 32);
    // c1 = relu(GN(concat @ cW1^T))
    f32x4 acc2[8] = {};
    gemm_T<12>(bc, cW1p, 384, acc2, c16, q4);
    gn_t(acc2, gb_c1, true, q4);
    // c2 = c1 @ cW2^T (natural rows) -> scatter-add
    bf16x8 bc2[4];
#pragma unroll
    for (int k = 0; k < 4; k++) bc2[k] = pack_frag(acc2[2 * k], acc2[2 * k + 1]);
    f32x4 acc3[8] = {};
    gemm_T<4>(bc2, cW2, 128, acc3, c16, q4);
    float* dst = a_out + (size_t)h * 128 + q4 * 4;
#pragma unroll
    for (int t = 0; t < 8; t++)
#pragma unroll
        for (int r = 0; r < 4; r++) unsafeAtomicAdd(dst + t * 16 + r, acc3[t][r]);
}

// ---------------- nodeB: a=relu(GN(a)); a2=GN(a@lW^T); feat=relu(a2+res) ----------------
__global__ __launch_bounds__(256) void k_nodeB(
    const float* __restrict__ a_in, const float* __restrict__ gg, const float* __restrict__ gb,
    const u16* __restrict__ lW, const float* __restrict__ lg, const float* __restrict__ lb,
    const u16* __restrict__ res, u16* __restrict__ out_bf, float* __restrict__ out_f32) {
    int lane = threadIdx.x & 63, wv = threadIdx.x >> 6;
    int c16 = lane & 15, q4 = lane >> 4;
    int m0 = (blockIdx.x * 4 + wv) * 16;
    const float* xr = a_in + (size_t)(m0 + c16) * 128 + q4 * 8;
    float x[32];
#pragma unroll
    for (int k = 0; k < 4; k++) {
        float4 u0 = *reinterpret_cast<const float4*>(xr + k * 32);
        float4 u1 = *reinterpret_cast<const float4*>(xr + k * 32 + 4);
        x[k * 8 + 0] = u0.x; x[k * 8 + 1] = u0.y; x[k * 8 + 2] = u0.z; x[k * 8 + 3] = u0.w;
        x[k * 8 + 4] = u1.x; x[k * 8 + 5] = u1.y; x[k * 8 + 6] = u1.z; x[k * 8 + 7] = u1.w;
    }
    float s = 0.f, s2 = 0.f;
#pragma unroll
    for (int t = 0; t < 32; t++) { s += x[t]; s2 = fmaf(x[t], x[t], s2); }
    s += __shfl_xor(s, 16, 64); s += __shfl_xor(s, 32, 64);
    s2 += __shfl_xor(s2, 16, 64); s2 += __shfl_xor(s2, 32, 64);
    float mean = s * (1.f / 128.f);
    float var = fmaf(s2, 1.f / 128.f, -mean * mean);
    float rstd = rsqrtf(var + 1e-5f);
    bf16x8 a[4];
#pragma unroll
    for (int k = 0; k < 4; k++) {
        float4 g0 = *reinterpret_cast<const float4*>(gg + k * 32 + q4 * 8);
        float4 g1 = *reinterpret_cast<const float4*>(gg + k * 32 + q4 * 8 + 4);
        float4 b0 = *reinterpret_cast<const float4*>(gb + k * 32 + q4 * 8);
        float4 b1 = *reinterpret_cast<const float4*>(gb + k * 32 + q4 * 8 + 4);
        float gv[8] = {g0.x, g0.y, g0.z, g0.w, g1.x, g1.y, g1.z, g1.w};
        float bv[8] = {b0.x, b0.y, b0.z, b0.w, b1.x, b1.y, b1.z, b1.w};
        union { u16 s[8]; bf16x8 b; } t;
#pragma unroll
        for (int j = 0; j < 8; j++) {
            float y = fmaf((x[k * 8 + j] - mean) * rstd, gv[j], bv[j]);
            t.s[j] = f2bf(fmaxf(y, 0.f));
        }
        a[k] = t.b;
    }
    f32x4 acc[8] = {};
    gemm_acc<4>(a, lW, 128, acc, c16, q4);
    gn_c(acc, lg, lb, false, c16);
#pragma unroll
    for (int r = 0; r < 4; r++) {
        size_t row = m0 + q4 * 4 + r;
#pragma unroll
        for (int n = 0; n < 8; n++) {
            int col = n * 16 + c16;
            float y = acc[n][r] + bf2f(res[row * 128 + col]);
            y = fmaxf(y, 0.f);
            if (out_bf) out_bf[row * 128 + col] = f2bf(y);
            else out_f32[row * 128 + col] = y;
        }
    }
}

extern "C" void kernel_launch(void* const* d_in, const int* in_sizes, int n_in,
                              void* d_out, int out_size, void* d_ws, size_t ws_size,
                              hipStream_t stream) {
    const float* feat = (const float*)d_in[0];
    const float* turn = (const float*)d_in[1];
    const float* ctrl = (const float*)d_in[2];
    const float* inter = (const float*)d_in[3];
    const float* mctr = (const float*)d_in[4];
    const float* actors = (const float*)d_in[5];
    const float* actr = (const float*)d_in[6];
    const int* hi = (const int*)d_in[7];
    const int* wi = (const int*)d_in[8];
    const float* metaW = (const float*)d_in[9];
    const float* metag = (const float*)d_in[10];
    const float* metab = (const float*)d_in[11];
    const float* dW1 = (const float*)d_in[12];
    const float* db1 = (const float*)d_in[13];
    const float* dW2 = (const float*)d_in[14];
    const float* dg2 = (const float*)d_in[15];
    const float* dbt2 = (const float*)d_in[16];
    const float* qW = (const float*)d_in[17];
    const float* qg = (const float*)d_in[18];
    const float* qb = (const float*)d_in[19];
    const float* cW1 = (const float*)d_in[20];
    const float* cg1 = (const float*)d_in[21];
    const float* cb1 = (const float*)d_in[22];
    const float* cW2 = (const float*)d_in[23];
    const float* aW = (const float*)d_in[24];
    const float* ngg = (const float*)d_in[25];
    const float* ngb = (const float*)d_in[26];
    const float* lW = (const float*)d_in[27];
    const float* lg = (const float*)d_in[28];
    const float* lb = (const float*)d_in[29];

    char* ws = (char*)d_ws;
    u16* feat0 = (u16*)(ws);                    // 33554432 B
    u16* feat1 = (u16*)(ws + 33554432);         // 33554432 B
    u16* actb = (u16*)(ws + 67108864);          // 262144 B
    u16* wmWf = (u16*)(ws + 67371008);          // 32768 B
    u16* wdW2p = (u16*)(ws + 67403776);         // 65536 B
    u16* wqWp = (u16*)(ws + 67469312);          // 65536 B
    u16* wcW1p = (u16*)(ws + 67534848);         // 196608 B
    u16* wcW2 = (u16*)(ws + 67731456);          // 65536 B
    u16* waW = (u16*)(ws + 67796992);           // 65536 B
    u16* wlW = (u16*)(ws + 67862528);           // 65536 B
    float* wmWe = (float*)(ws + 67928064);      // 2048 B
    float* wdw1p = (float*)(ws + 67930112);     // 4096 B
    float* gball = (float*)(ws + 67934208);     // 6144 B (3 tables x 2 layers x 128 x {g,b})
    float* abuf = (float*)d_out;                // d_out doubles as f32 scatter buffer

    k_prep<<<1613, 256, 0, stream>>>(dW2, qW, cW1, cW2, aW, lW, actors, metaW, dW1, db1,
                                     dg2, dbt2, qg, qb, cg1, cb1,
                                     wdW2p, wqWp, wcW1p, wcW2, waW, wlW, actb, wmWf, wmWe,
                                     wdw1p, gball);
    k_meta<<<2048, 256, 0, stream>>>(feat, turn, ctrl, inter, wmWf, wmWe, metag, metab, feat0);
    for (int i = 0; i < 2; i++) {
        const u16* fcur = i ? feat1 : feat0;
        k_nodeA<<<2048, 256, 0, stream>>>(fcur, waW + i * 16384, abuf);
        k_edge<<<4096, 256, 0, stream>>>(hi, wi, mctr, actr, wdw1p + i * 512, wdW2p + i * 16384,
                                         gball + i * 256, fcur, wqWp + i * 16384,
                                         gball + 512 + i * 256, actb,
                                         wcW1p + i * 49152, gball + 1024 + i * 256,
                                         wcW2 + i * 16384, abuf);
        k_nodeB<<<2048, 256, 0, stream>>>(abuf, ngg + i * 128, ngb + i * 128, wlW + i * 16384,
                                          lg + i * 128, lb + i * 128, fcur,
                                          i ? nullptr : feat1, i ? (float*)d_out : nullptr);
    }
}

// Round 3
// 792.121 us; speedup vs baseline: 1.9722x; 1.9722x over previous
//
#include <hip/hip_runtime.h>
#include <stdint.h>

typedef unsigned short u16;
typedef __bf16 bf16x8 __attribute__((ext_vector_type(8)));
typedef float f32x4 __attribute__((ext_vector_type(4)));

__device__ __forceinline__ u16 f2bf(float f) {
    union { float f; unsigned u; } v; v.f = f;
    unsigned r = v.u + 0x7fffu + ((v.u >> 16) & 1u);
    return (u16)(r >> 16);
}
__device__ __forceinline__ float bf2f(u16 h) {
    union { unsigned u; float f; } v; v.u = ((unsigned)h) << 16; return v.f;
}
__device__ __forceinline__ bf16x8 as_frag(uint4 u) {
    union { uint4 u; bf16x8 b; } v; v.u = u; return v.b;
}
__device__ __forceinline__ bf16x8 ldg_frag(const u16* p) {
    return as_frag(*reinterpret_cast<const uint4*>(p));
}
// weight-row permutation so swapped-GEMM output packs into natural frag order
__device__ __forceinline__ int rowmap(int t, int i) {
    return 32 * (t >> 1) + 8 * (i >> 2) + 4 * (t & 1) + (i & 3);
}

// ---- normal orientation: C[row][col=chan], one A-group ----
template <int KT>
__device__ __forceinline__ void gemm_acc(const bf16x8* a, const u16* __restrict__ W, int ldw,
                                         f32x4* acc, int c16, int q4) {
#pragma unroll
    for (int n = 0; n < 8; n++) {
        const u16* wp = W + (size_t)(n * 16 + c16) * ldw + q4 * 8;
#pragma unroll
        for (int k = 0; k < KT; k++) {
            bf16x8 b = ldg_frag(wp + k * 32);
            acc[n] = __builtin_amdgcn_mfma_f32_16x16x32_bf16(a[k], b, acc[n], 0, 0, 0);
        }
    }
}

// ---- normal orientation, TWO A-groups sharing each weight B-frag load ----
template <int KT>
__device__ __forceinline__ void gemm_acc2(const bf16x8* a0, const bf16x8* a1,
                                          const u16* __restrict__ W, int ldw,
                                          f32x4* c0, f32x4* c1, int c16, int q4) {
#pragma unroll
    for (int n = 0; n < 8; n++) {
        const u16* wp = W + (size_t)(n * 16 + c16) * ldw + q4 * 8;
#pragma unroll
        for (int k = 0; k < KT; k++) {
            bf16x8 b = ldg_frag(wp + k * 32);
            c0[n] = __builtin_amdgcn_mfma_f32_16x16x32_bf16(a0[k], b, c0[n], 0, 0, 0);
            c1[n] = __builtin_amdgcn_mfma_f32_16x16x32_bf16(a1[k], b, c1[n], 0, 0, 0);
        }
    }
}

// ---- swapped orientation (A=pre-permuted weights), TWO B-groups per weight load ----
template <int KT>
__device__ __forceinline__ void gemm_T2(const bf16x8* b0, const bf16x8* b1,
                                        const u16* __restrict__ Wp, int ldw,
                                        f32x4* acc0, f32x4* acc1, int c16, int q4) {
#pragma unroll
    for (int t = 0; t < 8; t++) {
        const u16* wp = Wp + (size_t)(t * 16 + c16) * ldw + q4 * 8;
#pragma unroll
        for (int k = 0; k < KT; k++) {
            bf16x8 a = ldg_frag(wp + k * 32);
            acc0[t] = __builtin_amdgcn_mfma_f32_16x16x32_bf16(a, b0[k], acc0[t], 0, 0, 0);
            acc1[t] = __builtin_amdgcn_mfma_f32_16x16x32_bf16(a, b1[k], acc1[t], 0, 0, 0);
        }
    }
}

// GroupNorm on swapped layout: lane holds 32 chans of one edge
__device__ __forceinline__ void gn_t(f32x4* acc, const float* __restrict__ gb, bool relu, int q4) {
    float s = 0.f, s2 = 0.f;
#pragma unroll
    for (int t = 0; t < 8; t++)
#pragma unroll
        for (int r = 0; r < 4; r++) { float x = acc[t][r]; s += x; s2 = fmaf(x, x, s2); }
    s += __shfl_xor(s, 16, 64); s += __shfl_xor(s, 32, 64);
    s2 += __shfl_xor(s2, 16, 64); s2 += __shfl_xor(s2, 32, 64);
    float mean = s * (1.f / 128.f);
    float var = fmaf(s2, 1.f / 128.f, -mean * mean);
    float rstd = rsqrtf(var + 1e-5f);
#pragma unroll
    for (int t = 0; t < 8; t++) {
        const float4* g4 = reinterpret_cast<const float4*>(gb + (t * 16 + q4 * 4) * 2);
        float4 p01 = g4[0], p23 = g4[1];
        float gv[4] = {p01.x, p01.z, p23.x, p23.z};
        float bv[4] = {p01.y, p01.w, p23.y, p23.w};
#pragma unroll
        for (int r = 0; r < 4; r++) {
            float y = fmaf((acc[t][r] - mean) * rstd, gv[r], bv[r]);
            acc[t][r] = relu ? fmaxf(y, 0.f) : y;
        }
    }
}

__device__ __forceinline__ bf16x8 pack_frag(f32x4 lo, f32x4 hi) {
    union { u16 s[8]; bf16x8 b; } t;
#pragma unroll
    for (int j = 0; j < 4; j++) { t.s[j] = f2bf(lo[j]); t.s[4 + j] = f2bf(hi[j]); }
    return t.b;
}

// GroupNorm on C-layout acc[n][r] (node kernels)
__device__ __forceinline__ void gn_c(f32x4* acc, const float* __restrict__ g,
                                     const float* __restrict__ b, bool relu, int c16) {
    float gs[8], bs[8];
#pragma unroll
    for (int n = 0; n < 8; n++) { gs[n] = g[n * 16 + c16]; bs[n] = b[n * 16 + c16]; }
#pragma unroll
    for (int r = 0; r < 4; r++) {
        float s = 0.f, s2 = 0.f;
#pragma unroll
        for (int n = 0; n < 8; n++) { float x = acc[n][r]; s += x; s2 = fmaf(x, x, s2); }
#pragma unroll
        for (int m = 1; m < 16; m <<= 1) { s += __shfl_xor(s, m, 64); s2 += __shfl_xor(s2, m, 64); }
        float mean = s * (1.f / 128.f);
        float var = fmaf(s2, 1.f / 128.f, -mean * mean);
        float rstd = rsqrtf(var + 1e-5f);
#pragma unroll
        for (int n = 0; n < 8; n++) {
            float y = fmaf((acc[n][r] - mean) * rstd, gs[n], bs[n]);
            acc[n][r] = relu ? fmaxf(y, 0.f) : y;
        }
    }
}

// ---------------- prep ----------------
__global__ __launch_bounds__(256) void k_prep(
    const float* __restrict__ dW2s, const float* __restrict__ qWs, const float* __restrict__ cW1s,
    const float* __restrict__ cW2s, const float* __restrict__ aWs, const float* __restrict__ lWs,
    const float* __restrict__ actors, const float* __restrict__ metaW,
    const float* __restrict__ dW1s, const float* __restrict__ db1s,
    const float* __restrict__ dg2s, const float* __restrict__ dbt2s,
    const float* __restrict__ qgs, const float* __restrict__ qbs,
    const float* __restrict__ cg1s, const float* __restrict__ cb1s,
    u16* __restrict__ o_dW2p, u16* __restrict__ o_qW, u16* __restrict__ o_cW1p,
    u16* __restrict__ o_cW2, u16* __restrict__ o_aW, u16* __restrict__ o_lW,
    u16* __restrict__ o_actb, u16* __restrict__ o_mWf, float* __restrict__ o_mWe,
    float* __restrict__ o_dw1p, float* __restrict__ o_gb) {
    int idx = blockIdx.x * 256 + threadIdx.x;
    if (idx >= 412672) return;
    if (idx < 32768) {
        int i = idx >> 14, rem = idx & 16383, ro = rem >> 7, col = rem & 127;
        o_dW2p[idx] = f2bf(dW2s[i * 16384 + rowmap(ro >> 4, ro & 15) * 128 + col]);
    } else if (idx < 65536) {
        int j = idx - 32768; o_qW[j] = f2bf(qWs[j]);   // natural (used by nodeA)
    } else if (idx < 163840) {
        int j = idx - 65536, i = j / 49152, rem = j - i * 49152, ro = rem / 384, col = rem - ro * 384;
        o_cW1p[j] = f2bf(cW1s[i * 49152 + rowmap(ro >> 4, ro & 15) * 384 + col]);
    } else if (idx < 196608) { int j = idx - 163840; o_cW2[j] = f2bf(cW2s[j]); }
    else if (idx < 229376) { int j = idx - 196608; o_aW[j] = f2bf(aWs[j]); }
    else if (idx < 262144) { int j = idx - 229376; o_lW[j] = f2bf(lWs[j]); }
    else if (idx < 393216) { int j = idx - 262144; o_actb[j] = f2bf(actors[j]); }
    else if (idx < 409600) { int j = idx - 393216; o_mWf[j] = f2bf(metaW[(j >> 7) * 132 + (j & 127)]); }
    else if (idx < 410112) { int j = idx - 409600; o_mWe[j] = metaW[(j >> 2) * 132 + 128 + (j & 3)]; }
    else if (idx < 411136) {
        int j = idx - 410112, i = j >> 9, col = (j >> 2) & 127, t = j & 3;
        float v = (t == 0) ? dW1s[i * 256 + col * 2]
                : (t == 1) ? dW1s[i * 256 + col * 2 + 1]
                : (t == 2) ? db1s[i * 128 + col] : 0.f;
        o_dw1p[j] = v;
    } else {
        int j = idx - 411136;           // 3 tables x 2 layers x 128 x {g,b}
        int tb = j >> 9, rem = j & 511, i = rem >> 8, q = rem & 255, o = q >> 1, f = q & 1;
        const float* gsrc = (tb == 0) ? dg2s : (tb == 1) ? qgs : cg1s;
        const float* bsrc = (tb == 0) ? dbt2s : (tb == 1) ? qbs : cb1s;
        int src = i * 128 + rowmap(o >> 4, o & 15);
        o_gb[j] = f ? bsrc[src] : gsrc[src];
    }
}

// ---------------- meta ----------------
__global__ __launch_bounds__(256) void k_meta(
    const float* __restrict__ feat, const float* __restrict__ turn,
    const float* __restrict__ ctrl, const float* __restrict__ inter,
    const u16* __restrict__ mWf, const float* __restrict__ mWe,
    const float* __restrict__ g, const float* __restrict__ b, u16* __restrict__ out) {
    int lane = threadIdx.x & 63, wv = threadIdx.x >> 6;
    int c16 = lane & 15, q4 = lane >> 4;
    int m0 = (blockIdx.x * 4 + wv) * 16;
    bf16x8 a[4];
    const float* xr = feat + (size_t)(m0 + c16) * 128 + q4 * 8;
#pragma unroll
    for (int k = 0; k < 4; k++) {
        float4 u0 = *reinterpret_cast<const float4*>(xr + k * 32);
        float4 u1 = *reinterpret_cast<const float4*>(xr + k * 32 + 4);
        union { u16 s[8]; bf16x8 b; } t;
        t.s[0] = f2bf(u0.x); t.s[1] = f2bf(u0.y); t.s[2] = f2bf(u0.z); t.s[3] = f2bf(u0.w);
        t.s[4] = f2bf(u1.x); t.s[5] = f2bf(u1.y); t.s[6] = f2bf(u1.z); t.s[7] = f2bf(u1.w);
        a[k] = t.b;
    }
    f32x4 acc[8] = {};
    gemm_acc<4>(a, mWf, 128, acc, c16, q4);
#pragma unroll
    for (int r = 0; r < 4; r++) {
        int row = m0 + q4 * 4 + r;
        float t0 = turn[2 * row], t1 = turn[2 * row + 1];
        float cv = ctrl[row], iv = inter[row];
#pragma unroll
        for (int n = 0; n < 8; n++) {
            int col = n * 16 + c16;
            float4 we = reinterpret_cast<const float4*>(mWe)[col];
            acc[n][r] += t0 * we.x + t1 * we.y + cv * we.z + iv * we.w;
        }
    }
    gn_c(acc, g, b, true, c16);
#pragma unroll
    for (int r = 0; r < 4; r++) {
        size_t row = m0 + q4 * 4 + r;
#pragma unroll
        for (int n = 0; n < 8; n++) out[row * 128 + n * 16 + c16] = f2bf(acc[n][r]);
    }
}

// ---------------- nodeA: q_node = relu(GN(feat@qW^T)); a = feat@aW^T ----------------
__global__ __launch_bounds__(256) void k_nodeA(
    const u16* __restrict__ featb, const u16* __restrict__ qW, const u16* __restrict__ aW,
    const float* __restrict__ qg, const float* __restrict__ qb,
    u16* __restrict__ q_out, float* __restrict__ a_out) {
    int lane = threadIdx.x & 63, wv = threadIdx.x >> 6;
    int c16 = lane & 15, q4 = lane >> 4;
    int m0 = (blockIdx.x * 4 + wv) * 16;
    bf16x8 a[4];
    const u16* xr = featb + (size_t)(m0 + c16) * 128 + q4 * 8;
#pragma unroll
    for (int k = 0; k < 4; k++) a[k] = ldg_frag(xr + k * 32);
    f32x4 accq[8] = {}, acca[8] = {};
    gemm_acc<4>(a, qW, 128, accq, c16, q4);
    gemm_acc<4>(a, aW, 128, acca, c16, q4);
#pragma unroll
    for (int r = 0; r < 4; r++) {
        size_t row = m0 + q4 * 4 + r;
#pragma unroll
        for (int n = 0; n < 8; n++) a_out[row * 128 + n * 16 + c16] = acca[n][r];
    }
    gn_c(accq, qg, qb, true, c16);
#pragma unroll
    for (int r = 0; r < 4; r++) {
        size_t row = m0 + q4 * 4 + r;
#pragma unroll
        for (int n = 0; n < 8; n++) q_out[row * 128 + n * 16 + c16] = f2bf(accq[n][r]);
    }
}

// ---------------- edge: register-resident, 32 edges/wave, coalesced scatter ----------------
__global__ __launch_bounds__(256) void k_edge(
    const int* __restrict__ hi, const int* __restrict__ wi,
    const float* __restrict__ mctr, const float* __restrict__ actr,
    const float* __restrict__ dw1p, const u16* __restrict__ dW2p,
    const float* __restrict__ gb_d2,
    const u16* __restrict__ q_node, const u16* __restrict__ actb,
    const u16* __restrict__ cW1p, const float* __restrict__ gb_c1,
    const u16* __restrict__ cW2, float* __restrict__ a_out) {
    int lane = threadIdx.x & 63, wv = threadIdx.x >> 6;
    int c16 = lane & 15, q4 = lane >> 4;
    int bid = (int)blockIdx.x;
    bid = (bid & 7) * 256 + (bid >> 3);  // XCD swizzle (2048 = 8*256, bijective)
    int ebase = bid * 128 + wv * 32;
    int h0 = hi[ebase + c16], w0 = wi[ebase + c16];
    int h1 = hi[ebase + 16 + c16], w1 = wi[ebase + 16 + c16];
    // d1 = relu(d0 @ dW1^T + db1), built directly in B-frag layout (both groups)
    float dx0 = mctr[2 * h0] - actr[2 * w0], dy0 = mctr[2 * h0 + 1] - actr[2 * w0 + 1];
    float dx1 = mctr[2 * h1] - actr[2 * w1], dy1 = mctr[2 * h1 + 1] - actr[2 * w1 + 1];
    bf16x8 bd0[4], bd1[4];
    const float4* w4p = reinterpret_cast<const float4*>(dw1p);
#pragma unroll
    for (int k = 0; k < 4; k++) {
        union { u16 s[8]; bf16x8 b; } t0, t1;
#pragma unroll
        for (int j = 0; j < 8; j++) {
            float4 w4 = w4p[k * 32 + q4 * 8 + j];
            t0.s[j] = f2bf(fmaxf(fmaf(dx0, w4.x, fmaf(dy0, w4.y, w4.z)), 0.f));
            t1.s[j] = f2bf(fmaxf(fmaf(dx1, w4.x, fmaf(dy1, w4.y, w4.z)), 0.f));
        }
        bd0[k] = t0.b; bd1[k] = t1.b;
    }
    // d2 = relu(GN(d1 @ dW2^T)) — swapped, lane-local output
    f32x4 accA[8] = {}, accB[8] = {};
    gemm_T2<4>(bd0, bd1, dW2p, 128, accA, accB, c16, q4);
    gn_t(accA, gb_d2, true, q4);
    gn_t(accB, gb_d2, true, q4);
    // concat B-frags: [d2 | q_node[h] | actors[w]]
    bf16x8 bc0[12], bc1[12];
#pragma unroll
    for (int k = 0; k < 4; k++) {
        bc0[k] = pack_frag(accA[2 * k], accA[2 * k + 1]);
        bc1[k] = pack_frag(accB[2 * k], accB[2 * k + 1]);
    }
    const u16* qr0 = q_node + (size_t)h0 * 128 + q4 * 8;
    const u16* qr1 = q_node + (size_t)h1 * 128 + q4 * 8;
    const u16* ar0 = actb + (size_t)w0 * 128 + q4 * 8;
    const u16* ar1 = actb + (size_t)w1 * 128 + q4 * 8;
#pragma unroll
    for (int k = 0; k < 4; k++) {
        bc0[4 + k] = ldg_frag(qr0 + k * 32);
        bc1[4 + k] = ldg_frag(qr1 + k * 32);
        bc0[8 + k] = ldg_frag(ar0 + k * 32);
        bc1[8 + k] = ldg_frag(ar1 + k * 32);
    }
    // c1 = relu(GN(concat @ cW1^T)) — swapped
#pragma unroll
    for (int t = 0; t < 8; t++) { accA[t] = f32x4{0,0,0,0}; accB[t] = f32x4{0,0,0,0}; }
    gemm_T2<12>(bc0, bc1, cW1p, 384, accA, accB, c16, q4);
    gn_t(accA, gb_c1, true, q4);
    gn_t(accB, gb_c1, true, q4);
    // c2 = c1 @ cW2^T — NORMAL orientation so the scatter is coalesced
    bf16x8 ba0[4], ba1[4];
#pragma unroll
    for (int k = 0; k < 4; k++) {
        ba0[k] = pack_frag(accA[2 * k], accA[2 * k + 1]);
        ba1[k] = pack_frag(accB[2 * k], accB[2 * k + 1]);
    }
#pragma unroll
    for (int t = 0; t < 8; t++) { accA[t] = f32x4{0,0,0,0}; accB[t] = f32x4{0,0,0,0}; }
    gemm_acc2<4>(ba0, ba1, cW2, 128, accA, accB, c16, q4);
    // scatter: C[edge=q4*4+r][chan=n*16+c16] — 16 lanes contiguous per row
#pragma unroll
    for (int r = 0; r < 4; r++) {
        int hr0 = hi[ebase + q4 * 4 + r];
        int hr1 = hi[ebase + 16 + q4 * 4 + r];
        float* dst0 = a_out + (size_t)hr0 * 128 + c16;
        float* dst1 = a_out + (size_t)hr1 * 128 + c16;
#pragma unroll
        for (int n = 0; n < 8; n++) {
            unsafeAtomicAdd(dst0 + n * 16, accA[n][r]);
            unsafeAtomicAdd(dst1 + n * 16, accB[n][r]);
        }
    }
}

// ---------------- nodeB ----------------
__global__ __launch_bounds__(256) void k_nodeB(
    const float* __restrict__ a_in, const float* __restrict__ gg, const float* __restrict__ gb,
    const u16* __restrict__ lW, const float* __restrict__ lg, const float* __restrict__ lb,
    const u16* __restrict__ res, u16* __restrict__ out_bf, float* __restrict__ out_f32) {
    int lane = threadIdx.x & 63, wv = threadIdx.x >> 6;
    int c16 = lane & 15, q4 = lane >> 4;
    int m0 = (blockIdx.x * 4 + wv) * 16;
    const float* xr = a_in + (size_t)(m0 + c16) * 128 + q4 * 8;
    float x[32];
#pragma unroll
    for (int k = 0; k < 4; k++) {
        float4 u0 = *reinterpret_cast<const float4*>(xr + k * 32);
        float4 u1 = *reinterpret_cast<const float4*>(xr + k * 32 + 4);
        x[k * 8 + 0] = u0.x; x[k * 8 + 1] = u0.y; x[k * 8 + 2] = u0.z; x[k * 8 + 3] = u0.w;
        x[k * 8 + 4] = u1.x; x[k * 8 + 5] = u1.y; x[k * 8 + 6] = u1.z; x[k * 8 + 7] = u1.w;
    }
    float s = 0.f, s2 = 0.f;
#pragma unroll
    for (int t = 0; t < 32; t++) { s += x[t]; s2 = fmaf(x[t], x[t], s2); }
    s += __shfl_xor(s, 16, 64); s += __shfl_xor(s, 32, 64);
    s2 += __shfl_xor(s2, 16, 64); s2 += __shfl_xor(s2, 32, 64);
    float mean = s * (1.f / 128.f);
    float var = fmaf(s2, 1.f / 128.f, -mean * mean);
    float rstd = rsqrtf(var + 1e-5f);
    bf16x8 a[4];
#pragma unroll
    for (int k = 0; k < 4; k++) {
        float4 g0 = *reinterpret_cast<const float4*>(gg + k * 32 + q4 * 8);
        float4 g1 = *reinterpret_cast<const float4*>(gg + k * 32 + q4 * 8 + 4);
        float4 b0 = *reinterpret_cast<const float4*>(gb + k * 32 + q4 * 8);
        float4 b1 = *reinterpret_cast<const float4*>(gb + k * 32 + q4 * 8 + 4);
        float gv[8] = {g0.x, g0.y, g0.z, g0.w, g1.x, g1.y, g1.z, g1.w};
        float bv[8] = {b0.x, b0.y, b0.z, b0.w, b1.x, b1.y, b1.z, b1.w};
        union { u16 s[8]; bf16x8 b; } t;
#pragma unroll
        for (int j = 0; j < 8; j++) {
            float y = fmaf((x[k * 8 + j] - mean) * rstd, gv[j], bv[j]);
            t.s[j] = f2bf(fmaxf(y, 0.f));
        }
        a[k] = t.b;
    }
    f32x4 acc[8] = {};
    gemm_acc<4>(a, lW, 128, acc, c16, q4);
    gn_c(acc, lg, lb, false, c16);
#pragma unroll
    for (int r = 0; r < 4; r++) {
        size_t row = m0 + q4 * 4 + r;
#pragma unroll
        for (int n = 0; n < 8; n++) {
            int col = n * 16 + c16;
            float y = acc[n][r] + bf2f(res[row * 128 + col]);
            y = fmaxf(y, 0.f);
            if (out_bf) out_bf[row * 128 + col] = f2bf(y);
            else out_f32[row * 128 + col] = y;
        }
    }
}

extern "C" void kernel_launch(void* const* d_in, const int* in_sizes, int n_in,
                              void* d_out, int out_size, void* d_ws, size_t ws_size,
                              hipStream_t stream) {
    const float* feat = (const float*)d_in[0];
    const float* turn = (const float*)d_in[1];
    const float* ctrl = (const float*)d_in[2];
    const float* inter = (const float*)d_in[3];
    const float* mctr = (const float*)d_in[4];
    const float* actors = (const float*)d_in[5];
    const float* actr = (const float*)d_in[6];
    const int* hi = (const int*)d_in[7];
    const int* wi = (const int*)d_in[8];
    const float* metaW = (const float*)d_in[9];
    const float* metag = (const float*)d_in[10];
    const float* metab = (const float*)d_in[11];
    const float* dW1 = (const float*)d_in[12];
    const float* db1 = (const float*)d_in[13];
    const float* dW2 = (const float*)d_in[14];
    const float* dg2 = (const float*)d_in[15];
    const float* dbt2 = (const float*)d_in[16];
    const float* qW = (const float*)d_in[17];
    const float* qg = (const float*)d_in[18];
    const float* qb = (const float*)d_in[19];
    const float* cW1 = (const float*)d_in[20];
    const float* cg1 = (const float*)d_in[21];
    const float* cb1 = (const float*)d_in[22];
    const float* cW2 = (const float*)d_in[23];
    const float* aW = (const float*)d_in[24];
    const float* ngg = (const float*)d_in[25];
    const float* ngb = (const float*)d_in[26];
    const float* lW = (const float*)d_in[27];
    const float* lg = (const float*)d_in[28];
    const float* lb = (const float*)d_in[29];

    char* ws = (char*)d_ws;
    u16* feat0 = (u16*)(ws);                    // 33554432 B
    u16* feat1 = (u16*)(ws + 33554432);         // 33554432 B
    u16* qbuf = (u16*)(ws + 67108864);          // 33554432 B
    u16* actb = (u16*)(ws + 100663296);         // 262144 B
    u16* wmWf = (u16*)(ws + 100925440);         // 32768 B
    u16* wdW2p = (u16*)(ws + 100958208);        // 65536 B
    u16* wqW = (u16*)(ws + 101023744);          // 65536 B
    u16* wcW1p = (u16*)(ws + 101089280);        // 196608 B
    u16* wcW2 = (u16*)(ws + 101285888);         // 65536 B
    u16* waW = (u16*)(ws + 101351424);          // 65536 B
    u16* wlW = (u16*)(ws + 101416960);          // 65536 B
    float* wmWe = (float*)(ws + 101482496);     // 2048 B
    float* wdw1p = (float*)(ws + 101484544);    // 4096 B
    float* gball = (float*)(ws + 101488640);    // 6144 B
    float* abuf = (float*)d_out;                // d_out doubles as f32 scatter buffer

    k_prep<<<1613, 256, 0, stream>>>(dW2, qW, cW1, cW2, aW, lW, actors, metaW, dW1, db1,
                                     dg2, dbt2, qg, qb, cg1, cb1,
                                     wdW2p, wqW, wcW1p, wcW2, waW, wlW, actb, wmWf, wmWe,
                                     wdw1p, gball);
    k_meta<<<2048, 256, 0, stream>>>(feat, turn, ctrl, inter, wmWf, wmWe, metag, metab, feat0);
    for (int i = 0; i < 2; i++) {
        const u16* fcur = i ? feat1 : feat0;
        k_nodeA<<<2048, 256, 0, stream>>>(fcur, wqW + i * 16384, waW + i * 16384,
                                          qg + i * 128, qb + i * 128, qbuf, abuf);
        k_edge<<<2048, 256, 0, stream>>>(hi, wi, mctr, actr, wdw1p + i * 512, wdW2p + i * 16384,
                                         gball + i * 256, qbuf, actb,
                                         wcW1p + i * 49152, gball + 1024 + i * 256,
                                         wcW2 + i * 16384, abuf);
        k_nodeB<<<2048, 256, 0, stream>>>(abuf, ngg + i * 128, ngb + i * 128, wlW + i * 16384,
                                          lg + i * 128, lb + i * 128, fcur,
                                          i ? nullptr : feat1, i ? (float*)d_out : nullptr);
    }
}